// Round 8
// baseline (225.619 us; speedup 1.0000x reference)
//
#include <hip/hip_runtime.h>
#include <hip/hip_bf16.h>

// DTWLoss: out[b] = softDTW(sqdist(x,y)) - 0.5*(softDTW(sqdist(x,x)) + softDTW(sqdist(y,y)))
// B=64, N=M=512, F=256, gamma=0.1, BIG=1e8. Output: 64 fp32.
//
// Phase 1: convert x,y to bf16 + fp32 row norms.
// Phase 2: 192 batched MFMA GEMMs, 128x128 block tile, LDS double-buffered,
//          4 waves x (64x64 via 4x4 MFMA tiles). D stored bf16 in DIAGONAL-
//          STAIRCASE layout: chunk (s,t), s=j+(i>>3), t=i>>3, elem off =
//          (s*64+t)*8 + (i&7). Epilogue: LDS transpose, then anti-diagonal
//          readout -> each store instr writes 8 FULL 128B lines.
//          R6/R7: XCD-contiguous work remap (xcd=L&7 owns 8 batches x 3p x
//          16 tiles = 4MB input = one L2) -> gemm out of top-5 (<66us).
// Phase 3: wavefront DTW (hardmin; |softmin-min|<=gamma*ln3/cell, total <=112
//          vs 5242.88 threshold). R7 post-mortem: dtw pinned at ~67us
//          (~280cy/step) across 4 prefetch schemes because 192 single-wave
//          blocks = ONE wave per SIMD: a lone wave cannot hide its own
//          16-op serial fmin/add chain; VALUBusy 9.4% vs 18.75% ceiling ->
//          ~50% of cycles stalled. R8: PAIR MATRICES PER SIMD. 24 blocks x
//          8 waves (512 thr); wave w owns matrix bid*8+w; round-robin wave->
//          SIMD gives 2 waves/SIMD -> one wave issues while the other sits
//          in its chain. Ring shrinks to 2 slots/wave (8x16KB=128KB/block,
//          1 block/CU); vmcnt(8), 16 DMAs in flight (~1 group cover; D is
//          L2/L3-resident after gemm).

#define SDTW_BIG   1e8f
#define LDA 40        // LDS row stride in shorts (32 + 8 pad)
#define DROWS 576     // staircase rows allocated per matrix (575 used + pad)
#define DMAT_ELEMS (DROWS * 512)   // 294912 elems = 589824 B per matrix

typedef __attribute__((ext_vector_type(8))) short short8;   // 8 bf16
typedef __attribute__((ext_vector_type(4))) float floatx4;  // mfma acc

__device__ __forceinline__ unsigned short f2bf(float f) {
    __hip_bfloat16 h = __float2bfloat16(f);
    return *reinterpret_cast<unsigned short*>(&h);
}
__device__ __forceinline__ float bf2f_lo(unsigned int u) {
    return __uint_as_float(u << 16);
}
__device__ __forceinline__ float bf2f_hi(unsigned int u) {
    return __uint_as_float(u & 0xFFFF0000u);
}

// shfl_up(x,1) as DPP wave_shr:1 (0x138): lane i <- lane i-1, pure VALU.
// Lane 0 keeps old (=x); caller overrides t==0.
__device__ __forceinline__ float dpp_shr1(float x) {
    const int xi = __float_as_int(x);
    const int r = __builtin_amdgcn_update_dpp(xi, xi, 0x138, 0xf, 0xf, false);
    return __int_as_float(r);
}

// async global->LDS DMA, 16B per lane. LDS dest is wave-uniform base; HW adds
// lane*16. Global src is PER-LANE (each lane's own VGPR address).
__device__ __forceinline__ void gload16(const unsigned short* g, void* l) {
    __builtin_amdgcn_global_load_lds(
        (const __attribute__((address_space(1))) void*)g,
        (__attribute__((address_space(3))) void*)l, 16, 0, 0);
}

// ---- Phase 1: fp32 -> bf16 + row sum-of-squares (fp32) --------------------
__global__ __launch_bounds__(256) void convert_norm_kernel(
    const float* __restrict__ x, const float* __restrict__ y,
    unsigned short* __restrict__ xb, unsigned short* __restrict__ yb,
    float* __restrict__ nx, float* __restrict__ ny) {
    const float* src = blockIdx.y ? y : x;
    unsigned short* dst = blockIdx.y ? yb : xb;
    float* nrm = blockIdx.y ? ny : nx;
    const int wave = threadIdx.x >> 6;
    const int lane = threadIdx.x & 63;
    const int row  = blockIdx.x * 4 + wave;          // 0..32767
    const float4 v = reinterpret_cast<const float4*>(src + (size_t)row * 256)[lane];
    float ss = v.x * v.x + v.y * v.y + v.z * v.z + v.w * v.w;
    ushort4 u;
    u.x = f2bf(v.x); u.y = f2bf(v.y); u.z = f2bf(v.z); u.w = f2bf(v.w);
    reinterpret_cast<ushort4*>(dst + (size_t)row * 256)[lane] = u;
    #pragma unroll
    for (int o = 32; o; o >>= 1) ss += __shfl_down(ss, o);
    if (lane == 0) nrm[row] = ss;
}

// ---- Phase 2: D = nA[i] + nB[j] - 2*A.B^T, staircase layout, LDS dbuf -----
// grid 3072 x 256 threads (1-D; explicit XCD-contiguous remap inside).
// 128x128 tile/block; wave (wr,wc) does the 64x64 quadrant via 4x4 MFMA
// tiles. K = 8 chunks x 32.
__global__ __launch_bounds__(256) void gemm_lds_kernel(
    const unsigned short* __restrict__ xb, const unsigned short* __restrict__ yb,
    const float* __restrict__ nx, const float* __restrict__ ny,
    unsigned short* __restrict__ Dws) {
    __shared__ short Sb[4][128 * LDA];     // Sb[0..1]=A dbuf, Sb[2..3]=B dbuf
    short (*Ab)[128 * LDA] = Sb;
    short (*Bb)[128 * LDA] = Sb + 2;

    // XCD-contiguous work remap (dispatch round-robin heuristic: XCD = L&7).
    // XCD k owns w in [k*384,(k+1)*384) = 8 batches x {3 p-types x 16 tiles}.
    // Per-XCD distinct input = 8 x (xb[b]+yb[b]) = 4MB = one L2.
    const int L    = blockIdx.x;          // 0..3071
    const int w    = (L & 7) * 384 + (L >> 3);
    const int b    = w / 48;              // batch 0..63
    const int rw   = w % 48;
    const int p    = rw >> 4;             // 0..2
    const int tile = rw & 15;
    const int i0base = (tile & 3) * 128;
    const int j0base = (tile >> 2) * 128;
    const int z = p * 64 + b;             // matrix index for Dws

    const unsigned short* A  = (p == 2) ? yb : xb;
    const unsigned short* Bm = (p == 1) ? xb : yb;
    const float* nA = (p == 2) ? ny : nx;
    const float* nB = (p == 1) ? nx : ny;
    A  += (size_t)b * (512 * 256);
    Bm += (size_t)b * (512 * 256);
    nA += b * 512;
    nB += b * 512;
    unsigned short* Dmat = Dws + (size_t)z * DMAT_ELEMS;

    const int tid  = threadIdx.x;
    const int wave = tid >> 6;
    const int lane = tid & 63;
    const int quad = lane >> 4;
    const int l16  = lane & 15;
    const int wr = wave >> 1, wc = wave & 1;

    // Staging: thread tid handles 16B quarters (row=tid>>2, q=tid&3) of rows
    // [0,64) and [64,128) for both A and B tiles.
    const int srow = tid >> 2;
    const int sq   = tid & 3;
    const short8* gA0 = reinterpret_cast<const short8*>(A  + (size_t)(i0base + srow)      * 256 + sq * 8);
    const short8* gA1 = reinterpret_cast<const short8*>(A  + (size_t)(i0base + srow + 64) * 256 + sq * 8);
    const short8* gB0 = reinterpret_cast<const short8*>(Bm + (size_t)(j0base + srow)      * 256 + sq * 8);
    const short8* gB1 = reinterpret_cast<const short8*>(Bm + (size_t)(j0base + srow + 64) * 256 + sq * 8);
    const int lO0 = srow * LDA + sq * 8;
    const int lO1 = (srow + 64) * LDA + sq * 8;

    // Preload chunk 0 -> buf 0.
    {
        short8 ra0 = gA0[0], ra1 = gA1[0], rb0 = gB0[0], rb1 = gB1[0];
        *reinterpret_cast<short8*>(&Ab[0][lO0]) = ra0;
        *reinterpret_cast<short8*>(&Ab[0][lO1]) = ra1;
        *reinterpret_cast<short8*>(&Bb[0][lO0]) = rb0;
        *reinterpret_cast<short8*>(&Bb[0][lO1]) = rb1;
    }
    __syncthreads();

    floatx4 acc[4][4];
    #pragma unroll
    for (int mt = 0; mt < 4; ++mt)
        #pragma unroll
        for (int nt = 0; nt < 4; ++nt) acc[mt][nt] = (floatx4){0.f, 0.f, 0.f, 0.f};

    #pragma unroll
    for (int c = 0; c < 8; ++c) {
        const int cb = c & 1;
        short8 na0, na1, nb0, nb1;
        if (c < 7) {                      // issue next chunk's global loads
            na0 = gA0[(c + 1) * 4]; na1 = gA1[(c + 1) * 4];
            nb0 = gB0[(c + 1) * 4]; nb1 = gB1[(c + 1) * 4];
        }
        short8 af[4], bfr[4];
        #pragma unroll
        for (int mt = 0; mt < 4; ++mt)
            af[mt] = *reinterpret_cast<const short8*>(&Ab[cb][(wr * 64 + mt * 16 + l16) * LDA + quad * 8]);
        #pragma unroll
        for (int nt = 0; nt < 4; ++nt)
            bfr[nt] = *reinterpret_cast<const short8*>(&Bb[cb][(wc * 64 + nt * 16 + l16) * LDA + quad * 8]);
        #pragma unroll
        for (int mt = 0; mt < 4; ++mt)
            #pragma unroll
            for (int nt = 0; nt < 4; ++nt)
                acc[mt][nt] = __builtin_amdgcn_mfma_f32_16x16x32_bf16(af[mt], bfr[nt], acc[mt][nt], 0, 0, 0);
        if (c < 7) {                      // stage next chunk after MFMA burst
            *reinterpret_cast<short8*>(&Ab[1 - cb][lO0]) = na0;
            *reinterpret_cast<short8*>(&Ab[1 - cb][lO1]) = na1;
            *reinterpret_cast<short8*>(&Bb[1 - cb][lO0]) = nb0;
            *reinterpret_cast<short8*>(&Bb[1 - cb][lO1]) = nb1;
            __syncthreads();
        }
    }

    // ---- Epilogue: LDS transpose -> staircase full-line stores ------------
    // C/D layout col=lane&15, row=quad*4+reg (m89-verified). Each wave owns a
    // private 8KB region (64 cols x 64 rows bf16, col-major, 16B units
    // XOR-swizzled by (col&7)). Wave-local RAW -> no barrier between write
    // and read. One __syncthreads first: regions alias Ab[1]/Bb[*], which
    // other waves still read in chunk 7.
    __syncthreads();
    short* ep = &Sb[0][0] + wave * 4096;
    #pragma unroll
    for (int mt = 0; mt < 4; ++mt) {
        const int ibase = i0base + wr * 64 + mt * 16 + quad * 4;
        const float4 nv = *reinterpret_cast<const float4*>(nA + ibase);
        const int u   = 2 * mt + (quad >> 1);   // logical 16B-unit (0..7)
        const int sub = (quad & 1) * 4;         // short offset within unit
        #pragma unroll
        for (int nt = 0; nt < 4; ++nt) {
            const int cl = nt * 16 + l16;       // local col 0..63
            const float y2 = nB[j0base + wc * 64 + cl];
            ushort4 pk;
            pk.x = f2bf(nv.x + y2 - 2.0f * acc[mt][nt][0]);
            pk.y = f2bf(nv.y + y2 - 2.0f * acc[mt][nt][1]);
            pk.z = f2bf(nv.z + y2 - 2.0f * acc[mt][nt][2]);
            pk.w = f2bf(nv.w + y2 - 2.0f * acc[mt][nt][3]);
            const int pu = u ^ (cl & 7);
            *reinterpret_cast<ushort4*>(ep + cl * 64 + pu * 8 + sub) = pk;
        }
    }
    // Anti-diagonal readout: iteration a0 covers 8 s-rows. Lane (a=l>>3,
    // r=l&7) supplies chunk (cl = s_off - r, unit u = r) -> global chunk
    // (s = Sbase + s_off, t = R0 + r). For each s the 8 r-lanes write
    // (R0+r)*16B consecutive = one FULL aligned 128B line (R0 mult of 8).
    {
        const int R0    = (i0base + wr * 64) >> 3;      // global 8-row index
        const int Sbase = j0base + wc * 64 + R0;
        const int a = lane >> 3, r = lane & 7;
        #pragma unroll
        for (int a0 = 0; a0 < 9; ++a0) {
            const int s_off = a0 * 8 + a;
            const int cl = s_off - r;                   // local col
            if (cl >= 0 && cl < 64) {
                const int pu = r ^ (cl & 7);
                const short8 v = *reinterpret_cast<const short8*>(ep + cl * 64 + pu * 8);
                *reinterpret_cast<short8*>(
                    Dmat + (size_t)(Sbase + s_off) * 512 + (R0 + r) * 8) = v;
            }
        }
    }
}

// ---- Phase 3: hardmin DTW, 8 waves/block (2 matrices per SIMD) ------------
// grid 24 x 512 threads. Wave wv owns matrix z = blockIdx.x*8 + wv; lane t
// owns rows [8t, 8t+8). Step s: lane t computes column j = s - t. 576 steps
// in 72 groups of 8. Staircase layout: group load = 8x fully-coalesced 1KB
// global_load_lds (per-lane src base + t*16B; uniform LDS dest + HW lane*16).
// Per-wave ring: 2 slots x 8KB (8 waves x 16KB = 128KB/block, 1 block/CU).
// 16 DMAs in flight; vmcnt(8) per group (~1 group of cover; D is L2/L3-warm
// after gemm). No __syncthreads: waves fully independent, disjoint LDS.

#define DTW_ISSUE(gidx, slot)                                                 \
    {                                                                         \
        int s8_ = (gidx) * 8;                                                 \
        if (s8_ > 568) s8_ = 568;   /* keep s in [0,575] (pad rows) */        \
        const unsigned short* gsrc_ = Dmat + (size_t)s8_ * 512 + t * 8;       \
        _Pragma("unroll")                                                     \
        for (int k = 0; k < 8; ++k)                                           \
            gload16(gsrc_ + k * 512, (void*)&wring[((slot) * 8 + k) * 64]);   \
    }

#define DTW_COMPG(buf, gidx)                                                  \
    {                                                                         \
        const int s0_ = (gidx) * 8;                                           \
        _Pragma("unroll")                                                     \
        for (int k = 0; k < 8; ++k) {                                         \
            const int j = s0_ + k - t;                                        \
            const float recv = dpp_shr1(bot);                                 \
            float u0 = u1s;                                                   \
            float u1 = recv;                                                  \
            u1s = recv;                                                       \
            if (t == 0) { u1 = SDTW_BIG; u0 = (j == 0) ? 0.0f : SDTW_BIG; }   \
            else if (j == 0) { u0 = SDTW_BIG; }                               \
            if (j >= 0 && j < 512) {                                          \
                float d[8];                                                   \
                d[0] = bf2f_lo(buf[k].x); d[1] = bf2f_hi(buf[k].x);           \
                d[2] = bf2f_lo(buf[k].y); d[3] = bf2f_hi(buf[k].y);           \
                d[4] = bf2f_lo(buf[k].z); d[5] = bf2f_hi(buf[k].z);           \
                d[6] = bf2f_lo(buf[k].w); d[7] = bf2f_hi(buf[k].w);           \
                float e[8];                                                   \
                e[0] = fminf(u0, prev[0]);                                    \
                _Pragma("unroll")                                             \
                for (int r = 1; r < 8; ++r) e[r] = fminf(prev[r - 1], prev[r]); \
                float c = d[0] + fminf(e[0], u1);                             \
                float nv[8]; nv[0] = c;                                       \
                _Pragma("unroll")                                             \
                for (int r = 1; r < 8; ++r) { c = d[r] + fminf(e[r], c); nv[r] = c; } \
                _Pragma("unroll")                                             \
                for (int r = 0; r < 8; ++r) prev[r] = nv[r];                  \
                bot = c;                                                      \
            }                                                                 \
        }                                                                     \
    }

// One group: wait oldest DMA group (vmcnt(8): 16 outstanding -> oldest 8
// landed) -> ds_read slot -> drain lgkm (regs hold data; slot free) ->
// issue DMA for group g+2 into this slot -> compute.
#define DTW_GROUP(gidx, slot)                                                 \
    {                                                                         \
        asm volatile("s_waitcnt vmcnt(8)" ::: "memory");                      \
        _Pragma("unroll")                                                     \
        for (int k = 0; k < 8; ++k) cur[k] = wring[((slot) * 8 + k) * 64 + t];\
        asm volatile("s_waitcnt lgkmcnt(0)" ::: "memory");                    \
        DTW_ISSUE((gidx) + 2, slot)                                           \
        DTW_COMPG(cur, gidx)                                                  \
    }

__global__ __launch_bounds__(512) void dtw_wave_kernel(
    const unsigned short* __restrict__ Dws, float* __restrict__ out) {
    __shared__ uint4 ring[8 * 2 * 8 * 64];   // 128KB: 8 waves x 2 slots x 8KB
    const int wv = threadIdx.x >> 6;     // wave 0..7
    const int t  = threadIdx.x & 63;     // lane 0..63
    const int z  = blockIdx.x * 8 + wv;  // matrix 0..191 = p*64 + b
    const int p  = z >> 6;
    const int b  = z & 63;
    const unsigned short* Dmat = Dws + (size_t)z * DMAT_ELEMS;
    uint4* wring = ring + wv * (2 * 8 * 64);

    float prev[8];                        // R[8t+r, j-1]
    #pragma unroll
    for (int r = 0; r < 8; ++r) prev[r] = SDTW_BIG;
    float bot = SDTW_BIG;                 // bottom-row value after last step
    float u1s = SDTW_BIG;                 // dpp received last step

    uint4 cur[8];

    // Prologue: fill the ring (groups 0..1, 16 DMA loads in flight).
    DTW_ISSUE(0, 0)
    DTW_ISSUE(1, 1)

    // 72 groups; issue side runs 2 ahead (groups 72/73 clamp to row 568 --
    // harmless, keeps the vmcnt bookkeeping uniform).
    for (int gg = 0; gg < 36; ++gg) {
        const int g = gg * 2;
        DTW_GROUP(g + 0, 0)
        DTW_GROUP(g + 1, 1)
    }

    asm volatile("s_waitcnt vmcnt(0)" ::: "memory");  // drain tail DMAs

    if (t == 63) {                // bot == R[511,511]
        const float coef = (p == 0) ? 1.0f : -0.5f;
        atomicAdd(&out[b], coef * bot);
    }
}

extern "C" void kernel_launch(void* const* d_in, const int* in_sizes, int n_in,
                              void* d_out, int out_size, void* d_ws, size_t ws_size,
                              hipStream_t stream) {
    const float* x = (const float*)d_in[0];
    const float* y = (const float*)d_in[1];
    float* out = (float*)d_out;
    char* ws = (char*)d_ws;

    // ws layout (bytes):
    //   [0, 113246208)              D bf16 staircase, 192 x 294912 elems
    //   [113246208, 130023424)      xb bf16
    //   [130023424, 146800640)      yb bf16
    //   [146800640, 146931712)      nx fp32
    //   [146931712, 147062784)      ny fp32
    unsigned short* Dws = (unsigned short*)ws;
    unsigned short* xb  = (unsigned short*)(ws + 113246208);
    unsigned short* yb  = (unsigned short*)(ws + 130023424);
    float* nx = (float*)(ws + 146800640);
    float* ny = (float*)(ws + 146931712);

    hipMemsetAsync(d_out, 0, 64 * sizeof(float), stream);
    convert_norm_kernel<<<dim3(8192, 2), 256, 0, stream>>>(x, y, xb, yb, nx, ny);
    gemm_lds_kernel<<<3072, 256, 0, stream>>>(xb, yb, nx, ny, Dws);
    dtw_wave_kernel<<<24, 512, 0, stream>>>(Dws, out);
}

// Round 9
// 188.082 us; speedup vs baseline: 1.1996x; 1.1996x over previous
//
#include <hip/hip_runtime.h>
#include <hip/hip_bf16.h>

// DTWLoss: out[b] = softDTW(sqdist(x,y)) - 0.5*(softDTW(sqdist(x,x)) + softDTW(sqdist(y,y)))
// B=64, N=M=512, F=256, gamma=0.1, BIG=1e8. Output: 64 fp32.
//
// Phase 1: convert x,y to bf16 + fp32 row norms.
// Phase 2: 192 batched MFMA GEMMs, 128x128 tile, LDS dbuf, staircase-layout
//          D (chunk (s,t): s=j+(i>>3), t=i>>3 at elems (s*64+t)*8+(i&7)),
//          full-128B-line stores, XCD-contiguous work remap (R7: gemm <66us).
// Phase 3: wavefront DTW (hardmin; |softmin-min|<=gamma*ln3/cell, total <=112
//          vs 5242.88 threshold). R8 post-mortem: 2 waves/SIMD regressed
//          (89us) because per-SIMD issue hit 78% -> each step issues ~70
//          wave64 VALU (~140 SIMD-cy) vs a ~280cy wall; the kernel is
//          ISSUE-COUNT-bound, not latency-bound. R9: back to 192x64 (R7,
//          67us) and cut issue: (a) v_min3 fusion c=d+min3(a,b,c), (b)
//          3-phase loop -- steady groups 12..59 (s in [96,479]) have ALL
//          lanes valid and j!=0, so drop exec-mask guards entirely, (c)
//          override-then-store u1s so t==0 needs 1 cndmask/step. Steady
//          issue ~70 -> ~32 instrs/step.

#define SDTW_BIG   1e8f
#define LDA 40        // LDS row stride in shorts (32 + 8 pad)
#define DROWS 576     // staircase rows allocated per matrix (575 used + pad)
#define DMAT_ELEMS (DROWS * 512)   // 294912 elems = 589824 B per matrix

typedef __attribute__((ext_vector_type(8))) short short8;   // 8 bf16
typedef __attribute__((ext_vector_type(4))) float floatx4;  // mfma acc

__device__ __forceinline__ unsigned short f2bf(float f) {
    __hip_bfloat16 h = __float2bfloat16(f);
    return *reinterpret_cast<unsigned short*>(&h);
}
__device__ __forceinline__ float bf2f_lo(unsigned int u) {
    return __uint_as_float(u << 16);
}
__device__ __forceinline__ float bf2f_hi(unsigned int u) {
    return __uint_as_float(u & 0xFFFF0000u);
}

// shfl_up(x,1) as DPP wave_shr:1 (0x138): lane i <- lane i-1, pure VALU.
// Lane 0 keeps old (=x); caller overrides t==0.
__device__ __forceinline__ float dpp_shr1(float x) {
    const int xi = __float_as_int(x);
    const int r = __builtin_amdgcn_update_dpp(xi, xi, 0x138, 0xf, 0xf, false);
    return __int_as_float(r);
}

// async global->LDS DMA, 16B per lane. LDS dest is wave-uniform base; HW adds
// lane*16. Global src is PER-LANE (each lane's own VGPR address).
__device__ __forceinline__ void gload16(const unsigned short* g, void* l) {
    __builtin_amdgcn_global_load_lds(
        (const __attribute__((address_space(1))) void*)g,
        (__attribute__((address_space(3))) void*)l, 16, 0, 0);
}

// ---- Phase 1: fp32 -> bf16 + row sum-of-squares (fp32) --------------------
__global__ __launch_bounds__(256) void convert_norm_kernel(
    const float* __restrict__ x, const float* __restrict__ y,
    unsigned short* __restrict__ xb, unsigned short* __restrict__ yb,
    float* __restrict__ nx, float* __restrict__ ny) {
    const float* src = blockIdx.y ? y : x;
    unsigned short* dst = blockIdx.y ? yb : xb;
    float* nrm = blockIdx.y ? ny : nx;
    const int wave = threadIdx.x >> 6;
    const int lane = threadIdx.x & 63;
    const int row  = blockIdx.x * 4 + wave;          // 0..32767
    const float4 v = reinterpret_cast<const float4*>(src + (size_t)row * 256)[lane];
    float ss = v.x * v.x + v.y * v.y + v.z * v.z + v.w * v.w;
    ushort4 u;
    u.x = f2bf(v.x); u.y = f2bf(v.y); u.z = f2bf(v.z); u.w = f2bf(v.w);
    reinterpret_cast<ushort4*>(dst + (size_t)row * 256)[lane] = u;
    #pragma unroll
    for (int o = 32; o; o >>= 1) ss += __shfl_down(ss, o);
    if (lane == 0) nrm[row] = ss;
}

// ---- Phase 2: D = nA[i] + nB[j] - 2*A.B^T, staircase layout, LDS dbuf -----
// grid 3072 x 256 threads (1-D; explicit XCD-contiguous remap inside).
// 128x128 tile/block; wave (wr,wc) does the 64x64 quadrant via 4x4 MFMA
// tiles. K = 8 chunks x 32.
__global__ __launch_bounds__(256) void gemm_lds_kernel(
    const unsigned short* __restrict__ xb, const unsigned short* __restrict__ yb,
    const float* __restrict__ nx, const float* __restrict__ ny,
    unsigned short* __restrict__ Dws) {
    __shared__ short Sb[4][128 * LDA];     // Sb[0..1]=A dbuf, Sb[2..3]=B dbuf
    short (*Ab)[128 * LDA] = Sb;
    short (*Bb)[128 * LDA] = Sb + 2;

    // XCD-contiguous work remap (dispatch round-robin heuristic: XCD = L&7).
    // XCD k owns w in [k*384,(k+1)*384) = 8 batches x {3 p-types x 16 tiles}.
    // Per-XCD distinct input = 8 x (xb[b]+yb[b]) = 4MB = one L2.
    const int L    = blockIdx.x;          // 0..3071
    const int w    = (L & 7) * 384 + (L >> 3);
    const int b    = w / 48;              // batch 0..63
    const int rw   = w % 48;
    const int p    = rw >> 4;             // 0..2
    const int tile = rw & 15;
    const int i0base = (tile & 3) * 128;
    const int j0base = (tile >> 2) * 128;
    const int z = p * 64 + b;             // matrix index for Dws

    const unsigned short* A  = (p == 2) ? yb : xb;
    const unsigned short* Bm = (p == 1) ? xb : yb;
    const float* nA = (p == 2) ? ny : nx;
    const float* nB = (p == 1) ? nx : ny;
    A  += (size_t)b * (512 * 256);
    Bm += (size_t)b * (512 * 256);
    nA += b * 512;
    nB += b * 512;
    unsigned short* Dmat = Dws + (size_t)z * DMAT_ELEMS;

    const int tid  = threadIdx.x;
    const int wave = tid >> 6;
    const int lane = tid & 63;
    const int quad = lane >> 4;
    const int l16  = lane & 15;
    const int wr = wave >> 1, wc = wave & 1;

    // Staging: thread tid handles 16B quarters (row=tid>>2, q=tid&3) of rows
    // [0,64) and [64,128) for both A and B tiles.
    const int srow = tid >> 2;
    const int sq   = tid & 3;
    const short8* gA0 = reinterpret_cast<const short8*>(A  + (size_t)(i0base + srow)      * 256 + sq * 8);
    const short8* gA1 = reinterpret_cast<const short8*>(A  + (size_t)(i0base + srow + 64) * 256 + sq * 8);
    const short8* gB0 = reinterpret_cast<const short8*>(Bm + (size_t)(j0base + srow)      * 256 + sq * 8);
    const short8* gB1 = reinterpret_cast<const short8*>(Bm + (size_t)(j0base + srow + 64) * 256 + sq * 8);
    const int lO0 = srow * LDA + sq * 8;
    const int lO1 = (srow + 64) * LDA + sq * 8;

    // Preload chunk 0 -> buf 0.
    {
        short8 ra0 = gA0[0], ra1 = gA1[0], rb0 = gB0[0], rb1 = gB1[0];
        *reinterpret_cast<short8*>(&Ab[0][lO0]) = ra0;
        *reinterpret_cast<short8*>(&Ab[0][lO1]) = ra1;
        *reinterpret_cast<short8*>(&Bb[0][lO0]) = rb0;
        *reinterpret_cast<short8*>(&Bb[0][lO1]) = rb1;
    }
    __syncthreads();

    floatx4 acc[4][4];
    #pragma unroll
    for (int mt = 0; mt < 4; ++mt)
        #pragma unroll
        for (int nt = 0; nt < 4; ++nt) acc[mt][nt] = (floatx4){0.f, 0.f, 0.f, 0.f};

    #pragma unroll
    for (int c = 0; c < 8; ++c) {
        const int cb = c & 1;
        short8 na0, na1, nb0, nb1;
        if (c < 7) {                      // issue next chunk's global loads
            na0 = gA0[(c + 1) * 4]; na1 = gA1[(c + 1) * 4];
            nb0 = gB0[(c + 1) * 4]; nb1 = gB1[(c + 1) * 4];
        }
        short8 af[4], bfr[4];
        #pragma unroll
        for (int mt = 0; mt < 4; ++mt)
            af[mt] = *reinterpret_cast<const short8*>(&Ab[cb][(wr * 64 + mt * 16 + l16) * LDA + quad * 8]);
        #pragma unroll
        for (int nt = 0; nt < 4; ++nt)
            bfr[nt] = *reinterpret_cast<const short8*>(&Bb[cb][(wc * 64 + nt * 16 + l16) * LDA + quad * 8]);
        #pragma unroll
        for (int mt = 0; mt < 4; ++mt)
            #pragma unroll
            for (int nt = 0; nt < 4; ++nt)
                acc[mt][nt] = __builtin_amdgcn_mfma_f32_16x16x32_bf16(af[mt], bfr[nt], acc[mt][nt], 0, 0, 0);
        if (c < 7) {                      // stage next chunk after MFMA burst
            *reinterpret_cast<short8*>(&Ab[1 - cb][lO0]) = na0;
            *reinterpret_cast<short8*>(&Ab[1 - cb][lO1]) = na1;
            *reinterpret_cast<short8*>(&Bb[1 - cb][lO0]) = nb0;
            *reinterpret_cast<short8*>(&Bb[1 - cb][lO1]) = nb1;
            __syncthreads();
        }
    }

    // ---- Epilogue: LDS transpose -> staircase full-line stores ------------
    // C/D layout col=lane&15, row=quad*4+reg (m89-verified). Each wave owns a
    // private 8KB region (64 cols x 64 rows bf16, col-major, 16B units
    // XOR-swizzled by (col&7)). Wave-local RAW -> no barrier between write
    // and read. One __syncthreads first: regions alias Ab[1]/Bb[*], which
    // other waves still read in chunk 7.
    __syncthreads();
    short* ep = &Sb[0][0] + wave * 4096;
    #pragma unroll
    for (int mt = 0; mt < 4; ++mt) {
        const int ibase = i0base + wr * 64 + mt * 16 + quad * 4;
        const float4 nv = *reinterpret_cast<const float4*>(nA + ibase);
        const int u   = 2 * mt + (quad >> 1);   // logical 16B-unit (0..7)
        const int sub = (quad & 1) * 4;         // short offset within unit
        #pragma unroll
        for (int nt = 0; nt < 4; ++nt) {
            const int cl = nt * 16 + l16;       // local col 0..63
            const float y2 = nB[j0base + wc * 64 + cl];
            ushort4 pk;
            pk.x = f2bf(nv.x + y2 - 2.0f * acc[mt][nt][0]);
            pk.y = f2bf(nv.y + y2 - 2.0f * acc[mt][nt][1]);
            pk.z = f2bf(nv.z + y2 - 2.0f * acc[mt][nt][2]);
            pk.w = f2bf(nv.w + y2 - 2.0f * acc[mt][nt][3]);
            const int pu = u ^ (cl & 7);
            *reinterpret_cast<ushort4*>(ep + cl * 64 + pu * 8 + sub) = pk;
        }
    }
    // Anti-diagonal readout: iteration a0 covers 8 s-rows. Lane (a=l>>3,
    // r=l&7) supplies chunk (cl = s_off - r, unit u = r) -> global chunk
    // (s = Sbase + s_off, t = R0 + r). For each s the 8 r-lanes write
    // (R0+r)*16B consecutive = one FULL aligned 128B line (R0 mult of 8).
    {
        const int R0    = (i0base + wr * 64) >> 3;      // global 8-row index
        const int Sbase = j0base + wc * 64 + R0;
        const int a = lane >> 3, r = lane & 7;
        #pragma unroll
        for (int a0 = 0; a0 < 9; ++a0) {
            const int s_off = a0 * 8 + a;
            const int cl = s_off - r;                   // local col
            if (cl >= 0 && cl < 64) {
                const int pu = r ^ (cl & 7);
                const short8 v = *reinterpret_cast<const short8*>(ep + cl * 64 + pu * 8);
                *reinterpret_cast<short8*>(
                    Dmat + (size_t)(Sbase + s_off) * 512 + (R0 + r) * 8) = v;
            }
        }
    }
}

// ---- Phase 3: one-wave hardmin DTW, 3-phase loop, min3 chain --------------
// grid 192 x 64 threads (one wave). Lane t owns rows [8t, 8t+8).
// Step s: lane t computes column j = s - t. 576 steps in 72 groups of 8.
// Staircase layout: group load = 8x fully-coalesced 1KB global_load_lds
// (per-lane src base + t*16B; uniform LDS dest + HW lane*16).
// Ring: 6 slots x 8KB; 48 DMAs in flight; vmcnt(40) per group.
// Phases: groups 0..11 GUARDED (j<0 / j==0 cases live in s<96), groups
// 12..59 FAST (s in [96,479] -> j in [33,479]: every lane valid, j!=0 ->
// no exec-mask guards), groups 60..71 GUARDED (j>=512 cases).
// u1s convention: stores POST-OVERRIDE u1, so lane 0's next-step u0 is
// automatically BIG (1 cndmask/step in FAST).

#define DTW_ISSUE(gidx, slot)                                                 \
    {                                                                         \
        int s8_ = (gidx) * 8;                                                 \
        if (s8_ > 568) s8_ = 568;   /* keep s in [0,575] (pad rows) */        \
        const unsigned short* gsrc_ = Dmat + (size_t)s8_ * 512 + t * 8;       \
        _Pragma("unroll")                                                     \
        for (int k = 0; k < 8; ++k)                                           \
            gload16(gsrc_ + k * 512, (void*)&ring[((slot) * 8 + k) * 64]);    \
    }

#define DTW_UNPACK(buf, k, d)                                                 \
    d[0] = bf2f_lo(buf[k].x); d[1] = bf2f_hi(buf[k].x);                       \
    d[2] = bf2f_lo(buf[k].y); d[3] = bf2f_hi(buf[k].y);                       \
    d[4] = bf2f_lo(buf[k].z); d[5] = bf2f_hi(buf[k].z);                       \
    d[6] = bf2f_lo(buf[k].w); d[7] = bf2f_hi(buf[k].w);

// min3-fused cell chain: c_r = d_r + min3(prev[r-1], prev[r], c_{r-1}).
#define DTW_CELLS(d, u0, u1)                                                  \
    {                                                                         \
        float c = d[0] + fminf(fminf(u0, prev[0]), u1);                       \
        float nv[8]; nv[0] = c;                                               \
        _Pragma("unroll")                                                     \
        for (int r = 1; r < 8; ++r) {                                         \
            c = d[r] + fminf(fminf(prev[r - 1], prev[r]), c);                 \
            nv[r] = c;                                                        \
        }                                                                     \
        _Pragma("unroll")                                                     \
        for (int r = 0; r < 8; ++r) prev[r] = nv[r];                          \
        bot = c;                                                              \
    }

// Guarded step (ramp-up / ramp-down): full j-range + j==0 handling.
#define DTW_COMPG(buf, gidx)                                                  \
    {                                                                         \
        const int s0_ = (gidx) * 8;                                           \
        _Pragma("unroll")                                                     \
        for (int k = 0; k < 8; ++k) {                                         \
            const int j = s0_ + k - t;                                        \
            const float recv = dpp_shr1(bot);                                 \
            const float u1 = (t == 0) ? SDTW_BIG : recv;                      \
            float u0 = u1s;                                                   \
            if (j == 0) u0 = (t == 0) ? 0.0f : SDTW_BIG;                      \
            u1s = u1;                                                         \
            if (j >= 0 && j < 512) {                                          \
                float d[8];                                                   \
                DTW_UNPACK(buf, k, d)                                         \
                DTW_CELLS(d, u0, u1)                                          \
            }                                                                 \
        }                                                                     \
    }

// Fast step (steady state, s in [96,479]): all lanes valid, j!=0.
#define DTW_COMPF(buf, gidx)                                                  \
    {                                                                         \
        _Pragma("unroll")                                                     \
        for (int k = 0; k < 8; ++k) {                                         \
            const float recv = dpp_shr1(bot);                                 \
            const float u1 = (t == 0) ? SDTW_BIG : recv;                      \
            const float u0 = u1s;                                             \
            u1s = u1;                                                         \
            float d[8];                                                       \
            DTW_UNPACK(buf, k, d)                                             \
            DTW_CELLS(d, u0, u1)                                              \
        }                                                                     \
    }

// One group: wait oldest DMA group -> ds_read slot -> drain lgkm (regs hold
// data; slot free) -> issue DMA for group g+6 into this slot -> compute.
#define DTW_GROUP_G(gidx, slot)                                               \
    {                                                                         \
        asm volatile("s_waitcnt vmcnt(40)" ::: "memory");                     \
        _Pragma("unroll")                                                     \
        for (int k = 0; k < 8; ++k) cur[k] = ring[((slot) * 8 + k) * 64 + t]; \
        asm volatile("s_waitcnt lgkmcnt(0)" ::: "memory");                    \
        DTW_ISSUE((gidx) + 6, slot)                                           \
        DTW_COMPG(cur, gidx)                                                  \
    }

#define DTW_GROUP_F(gidx, slot)                                               \
    {                                                                         \
        asm volatile("s_waitcnt vmcnt(40)" ::: "memory");                     \
        _Pragma("unroll")                                                     \
        for (int k = 0; k < 8; ++k) cur[k] = ring[((slot) * 8 + k) * 64 + t]; \
        asm volatile("s_waitcnt lgkmcnt(0)" ::: "memory");                    \
        DTW_ISSUE((gidx) + 6, slot)                                           \
        DTW_COMPF(cur, gidx)                                                  \
    }

__global__ __launch_bounds__(64) void dtw_wave_kernel(
    const unsigned short* __restrict__ Dws, float* __restrict__ out) {
    __shared__ uint4 ring[6 * 8 * 64];   // 48KB: 6 slots x (8 s-rows x 1KB)
    const int z = blockIdx.x;            // p*64 + b
    const int p = z >> 6;
    const int b = z & 63;
    const unsigned short* Dmat = Dws + (size_t)z * DMAT_ELEMS;
    const int t = threadIdx.x;           // lane 0..63

    float prev[8];                        // R[8t+r, j-1]
    #pragma unroll
    for (int r = 0; r < 8; ++r) prev[r] = SDTW_BIG;
    float bot = SDTW_BIG;                 // bottom-row value after last step
    float u1s = SDTW_BIG;                 // post-override u1 of last step

    uint4 cur[8];

    // Prologue: fill the ring (groups 0..5, 48 DMA loads in flight).
    DTW_ISSUE(0, 0)
    DTW_ISSUE(1, 1)
    DTW_ISSUE(2, 2)
    DTW_ISSUE(3, 3)
    DTW_ISSUE(4, 4)
    DTW_ISSUE(5, 5)

    // Ramp-up: groups 0..11 guarded.
    for (int gg = 0; gg < 2; ++gg) {
        const int g = gg * 6;
        DTW_GROUP_G(g + 0, 0)
        DTW_GROUP_G(g + 1, 1)
        DTW_GROUP_G(g + 2, 2)
        DTW_GROUP_G(g + 3, 3)
        DTW_GROUP_G(g + 4, 4)
        DTW_GROUP_G(g + 5, 5)
    }
    // Steady: groups 12..59 fast (s in [96,479] -> all lanes valid).
    for (int gg = 2; gg < 10; ++gg) {
        const int g = gg * 6;
        DTW_GROUP_F(g + 0, 0)
        DTW_GROUP_F(g + 1, 1)
        DTW_GROUP_F(g + 2, 2)
        DTW_GROUP_F(g + 3, 3)
        DTW_GROUP_F(g + 4, 4)
        DTW_GROUP_F(g + 5, 5)
    }
    // Ramp-down: groups 60..71 guarded (issue side clamps to row 568).
    for (int gg = 10; gg < 12; ++gg) {
        const int g = gg * 6;
        DTW_GROUP_G(g + 0, 0)
        DTW_GROUP_G(g + 1, 1)
        DTW_GROUP_G(g + 2, 2)
        DTW_GROUP_G(g + 3, 3)
        DTW_GROUP_G(g + 4, 4)
        DTW_GROUP_G(g + 5, 5)
    }

    asm volatile("s_waitcnt vmcnt(0)" ::: "memory");  // drain tail DMAs

    if (t == 63) {                // bot == R[511,511]
        const float coef = (p == 0) ? 1.0f : -0.5f;
        atomicAdd(&out[b], coef * bot);
    }
}

extern "C" void kernel_launch(void* const* d_in, const int* in_sizes, int n_in,
                              void* d_out, int out_size, void* d_ws, size_t ws_size,
                              hipStream_t stream) {
    const float* x = (const float*)d_in[0];
    const float* y = (const float*)d_in[1];
    float* out = (float*)d_out;
    char* ws = (char*)d_ws;

    // ws layout (bytes):
    //   [0, 113246208)              D bf16 staircase, 192 x 294912 elems
    //   [113246208, 130023424)      xb bf16
    //   [130023424, 146800640)      yb bf16
    //   [146800640, 146931712)      nx fp32
    //   [146931712, 147062784)      ny fp32
    unsigned short* Dws = (unsigned short*)ws;
    unsigned short* xb  = (unsigned short*)(ws + 113246208);
    unsigned short* yb  = (unsigned short*)(ws + 130023424);
    float* nx = (float*)(ws + 146800640);
    float* ny = (float*)(ws + 146931712);

    hipMemsetAsync(d_out, 0, 64 * sizeof(float), stream);
    convert_norm_kernel<<<dim3(8192, 2), 256, 0, stream>>>(x, y, xb, yb, nx, ny);
    gemm_lds_kernel<<<3072, 256, 0, stream>>>(xb, yb, nx, ny, Dws);
    dtw_wave_kernel<<<192, 64, 0, stream>>>(Dws, out);
}